// Round 8
// baseline (135.571 us; speedup 1.0000x reference)
//
#include <hip/hip_runtime.h>
#include <math.h>

#define B_  2
#define T_  2048
#define D_  512
#define H_  8
#define HD_ 64
#define QKVS (3*D_)   // 1536

typedef __bf16 bf16x8 __attribute__((ext_vector_type(8)));
typedef float  f32x4  __attribute__((ext_vector_type(4)));

__device__ inline unsigned short f2bf(float f) {   // RN-even fp32->bf16
  unsigned int u = __float_as_uint(f);
  return (unsigned short)((u + 0x7FFFu + ((u >> 16) & 1u)) >> 16);
}
__device__ inline unsigned int pack2bf(float lo, float hi) {
  return (unsigned int)f2bf(lo) | ((unsigned int)f2bf(hi) << 16);
}

// ---------------------------------------------------------------------------
// Fused cast fp32 -> bf16 for x, w_qkv, w_out in one launch (float4 units).
// ---------------------------------------------------------------------------
__global__ void cast_all(const float* __restrict__ x,
                         const float* __restrict__ wq,
                         const float* __restrict__ wo,
                         unsigned short* __restrict__ xb,
                         unsigned short* __restrict__ wqb,
                         unsigned short* __restrict__ wob) {
  const int n_x  = (B_ * T_ * D_) / 4;
  const int n_wq = (QKVS * D_) / 4;
  const int n_wo = (D_ * D_) / 4;
  int i = blockIdx.x * blockDim.x + threadIdx.x;
  const float* src; unsigned short* dst; int off;
  if (i < n_x)                    { src = x;  dst = xb;  off = i; }
  else if (i < n_x + n_wq)        { src = wq; dst = wqb; off = i - n_x; }
  else if (i < n_x + n_wq + n_wo) { src = wo; dst = wob; off = i - n_x - n_wq; }
  else return;
  float4 v = ((const float4*)src)[off];
  ushort4 o;
  o.x = f2bf(v.x); o.y = f2bf(v.y); o.z = f2bf(v.z); o.w = f2bf(v.w);
  ((ushort4*)dst)[off] = o;
}

// ---------------------------------------------------------------------------
// LDS-free, barrier-free MFMA GEMM (NT): C[M,N] = A[M,K]@Bw[N,K]^T + bias.
// Every MFMA fragment is a direct 16-B global load (L2-resident operands);
// register double-buffer prefetches step s+1 during step s's MFMAs.
// Block = 4 waves (2x2), block tile 64(rows)x128(cols); wave tile 32x64
// (2x4 accs = 8 independent MFMA chains). K = 32*KSTEPS.
// No LDS, no __syncthreads, no vmcnt(0) barrier drains.
// ---------------------------------------------------------------------------
template<int BF16OUT, int KSTEPS>
__global__ __launch_bounds__(256, 3)
void gemm_nt_direct(const unsigned short* __restrict__ A,
                    const unsigned short* __restrict__ Bw,
                    const float* __restrict__ bias, void* __restrict__ Cv,
                    int M, int N, int K) {
  const int tid = threadIdx.x;
  const int w  = tid >> 6, l = tid & 63;
  const int wr = w >> 1,  wc = w & 1;
  const int Q  = l >> 4,  c  = l & 15;
  const int rowbase = blockIdx.y * 64  + wr * 32;
  const int colbase = blockIdx.x * 128 + wc * 64;

  int aoff[2], boff[4];
  #pragma unroll
  for (int mi = 0; mi < 2; ++mi)
    aoff[mi] = (rowbase + mi * 16 + c) * K + Q * 8;
  #pragma unroll
  for (int ni = 0; ni < 4; ++ni)
    boff[ni] = (colbase + ni * 16 + c) * K + Q * 8;

  f32x4 acc[2][4] = {};
  bf16x8 af[2][2], bf[2][4];

  #pragma unroll
  for (int mi = 0; mi < 2; ++mi) af[0][mi] = *(const bf16x8*)(A  + aoff[mi]);
  #pragma unroll
  for (int ni = 0; ni < 4; ++ni) bf[0][ni] = *(const bf16x8*)(Bw + boff[ni]);

  #pragma unroll
  for (int s = 0; s < KSTEPS; ++s) {
    const int cur = s & 1, nxt = cur ^ 1;
    if (s < KSTEPS - 1) {
      const int k1 = (s + 1) * 32;
      #pragma unroll
      for (int mi = 0; mi < 2; ++mi)
        af[nxt][mi] = *(const bf16x8*)(A + aoff[mi] + k1);
      #pragma unroll
      for (int ni = 0; ni < 4; ++ni)
        bf[nxt][ni] = *(const bf16x8*)(Bw + boff[ni] + k1);
    }
    #pragma unroll
    for (int mi = 0; mi < 2; ++mi)
      #pragma unroll
      for (int ni = 0; ni < 4; ++ni)
        acc[mi][ni] = __builtin_amdgcn_mfma_f32_16x16x32_bf16(
            af[cur][mi], bf[cur][ni], acc[mi][ni], 0, 0, 0);
  }

  // Epilogue: D[row = Q*4 + r][col = c] per acc tile; add bias, store.
  #pragma unroll
  for (int mi = 0; mi < 2; ++mi) {
    #pragma unroll
    for (int ni = 0; ni < 4; ++ni) {
      const int col = colbase + ni * 16 + c;
      const float bv = bias[col];
      #pragma unroll
      for (int r = 0; r < 4; ++r) {
        const int row = rowbase + mi * 16 + Q * 4 + r;
        const float val = acc[mi][ni][r] + bv;
        if (BF16OUT)
          ((unsigned short*)Cv)[(size_t)row * N + col] = f2bf(val);
        else
          ((float*)Cv)[(size_t)row * N + col] = val;
      }
    }
  }
}

// ---------------------------------------------------------------------------
// Residue-class flash attention, 64-query stripes (exact R5 kernel).
// Block = (bh, slot); slot -> (g = slot/p, r = slot%p); stripe = queries
// [g*64, g*64+64) of residue r's subsequence (token t -> r + t*p).
// 4 waves share staged 32-key K/V tiles; V staged transposed (Vt[d][key]).
// ---------------------------------------------------------------------------
__global__ __launch_bounds__(256)
void attn_flash2(const unsigned short* __restrict__ qkv,
                 const int* __restrict__ periods,
                 unsigned short* __restrict__ ao) {
  const int bh = blockIdx.x, slot = blockIdx.y;
  int p = periods[bh]; if (p < 1) p = 1;
  const int g  = slot / p;
  const int r  = slot - g * p;
  const int L  = (T_ - 1 - r) / p + 1;   // tokens in this residue class
  const int q0 = g << 6;                 // stripe base (t-space)
  if (q0 >= L) return;
  const int b = bh >> 3, h = bh & 7;
  const int Lrem = L - q0;               // >= 1
  const int Nkb  = min(L, q0 + 64);      // keys needed by the whole block

  const int tid  = threadIdx.x;
  const int w    = tid >> 6;             // wave 0..3
  const int lane = tid & 63;
  const int Q = lane >> 4, c = lane & 15;

  __shared__ __align__(16) unsigned short Qs[64 * 72];  // 9216 B
  __shared__ __align__(16) unsigned short Ks[32 * 72];  // 4608 B
  __shared__ __align__(16) unsigned short Vt[64 * 40];  // 5120 B, [d][key]

  const size_t rowb = (size_t)b * T_ * QKVS + (size_t)h * HD_;

  // ---- stage Q stripe (64 rows x 64 halfs): 32 B per thread ----
  {
    const int u = tid >> 2, ch4 = (tid & 3) * 16;
    const int t = q0 + min(u, Lrem - 1);            // clamp (dup row, masked)
    const unsigned short* gq = qkv + rowb + (size_t)(r + t * p) * QKVS + ch4;
    int4 v0 = ((const int4*)gq)[0];
    int4 v1 = ((const int4*)gq)[1];
    *(int4*)&Qs[u * 72 + ch4 + 0] = v0;
    *(int4*)&Qs[u * 72 + ch4 + 8] = v1;
  }
  __syncthreads();
  bf16x8 qf[2];                          // B-frag: B[k=d=Q*8+j(+32)][n=q=c]
  qf[0] = *(const bf16x8*)&Qs[(w * 16 + c) * 72 + Q * 8];
  qf[1] = *(const bf16x8*)&Qs[(w * 16 + c) * 72 + Q * 8 + 32];

  const int qb      = w * 16;            // wave's query offset in stripe
  const int nqw     = min(16, Lrem - qb);// <=0 -> inactive wave (barriers only)
  const int qglob   = q0 + qb + c;       // this lane's query t-index
  const int mylastk = q0 + qb + 15;      // last key this wave can need

  float m_run = -3.0e38f, l_run = 0.f;
  f32x4 o[4] = {};
  const size_t kb = rowb + D_;
  const size_t vb = rowb + 2 * D_;

  // staging assignments (256 threads)
  const int krow = tid >> 3, koff = (tid & 7) * 8;      // K: 16B/thread
  const int vkey = tid & 31, vd0 = (tid >> 5) * 8;      // V: 16B/thread

  for (int k0 = 0; k0 < Nkb; k0 += 32) {
    // ---- stage K (row-major) + V (transposed) 32-key tiles ----
    {
      const int tk = min(k0 + krow, Nkb - 1);           // dup rows masked below
      const int tv = min(k0 + vkey, Nkb - 1);
      int4 kv = *(const int4*)(qkv + kb + (size_t)(r + tk * p) * QKVS + koff);
      int4 vv = *(const int4*)(qkv + vb + (size_t)(r + tv * p) * QKVS + vd0);
      unsigned short vh[8];
      *(int4*)vh = vv;
      __syncthreads();                   // prev iter's frag reads complete
      *(int4*)&Ks[krow * 72 + koff] = kv;
      #pragma unroll
      for (int j = 0; j < 8; ++j)
        Vt[(vd0 + j) * 40 + vkey] = vh[j];
      __syncthreads();
    }

    if (nqw > 0 && k0 <= mylastk) {
      // ---- S^T = K . Q^T  (two 16-key M-tiles, K-depth 64) ----
      f32x4 s[2];
      #pragma unroll
      for (int mt = 0; mt < 2; ++mt) {
        bf16x8 a0 = *(const bf16x8*)&Ks[(mt * 16 + c) * 72 + Q * 8];
        bf16x8 a1 = *(const bf16x8*)&Ks[(mt * 16 + c) * 72 + Q * 8 + 32];
        f32x4 acc = {};
        acc = __builtin_amdgcn_mfma_f32_16x16x32_bf16(a0, qf[0], acc, 0, 0, 0);
        acc = __builtin_amdgcn_mfma_f32_16x16x32_bf16(a1, qf[1], acc, 0, 0, 0);
        s[mt] = acc;
      }

      // ---- scale + causal mask + online softmax (per col q=c) ----
      float pvv[8];
      float tmax = -3.0e38f;
      #pragma unroll
      for (int mt = 0; mt < 2; ++mt)
        #pragma unroll
        for (int rg = 0; rg < 4; ++rg) {
          const int kk = k0 + mt * 16 + Q * 4 + rg;     // key t-index
          float v = s[mt][rg] * 0.125f;                 // 1/sqrt(HD)
          v = (kk <= qglob) ? v : -3.0e38f;
          pvv[mt * 4 + rg] = v;
          tmax = fmaxf(tmax, v);
        }
      tmax = fmaxf(tmax, __shfl_xor(tmax, 16));
      tmax = fmaxf(tmax, __shfl_xor(tmax, 32));
      const float m_new = fmaxf(m_run, tmax);
      const float alpha = __expf(m_run - m_new);
      float tsum = 0.f;
      #pragma unroll
      for (int i = 0; i < 8; ++i) { pvv[i] = __expf(pvv[i] - m_new); tsum += pvv[i]; }
      tsum += __shfl_xor(tsum, 16);
      tsum += __shfl_xor(tsum, 32);
      l_run = l_run * alpha + tsum;
      m_run = m_new;

      // ---- P^T: C-layout -> B-operand layout (8 shfl + 4 selects) ----
      unsigned int pk0[2], pk1[2];
      pk0[0] = pack2bf(pvv[0], pvv[1]); pk0[1] = pack2bf(pvv[2], pvv[3]);
      pk1[0] = pack2bf(pvv[4], pvv[5]); pk1[1] = pack2bf(pvv[6], pvv[7]);
      int dw[4];
      const int sq2 = (Q & 1) << 1;
      #pragma unroll
      for (int d = 0; d < 4; ++d) {
        const int src = ((sq2 + (d >> 1)) << 4) + c;
        const int v0 = __shfl((int)pk0[d & 1], src);
        const int v1 = __shfl((int)pk1[d & 1], src);
        dw[d] = (Q >= 2) ? v1 : v0;
      }
      int4 bi = make_int4(dw[0], dw[1], dw[2], dw[3]);
      bf16x8 pb = *(bf16x8*)&bi;

      // ---- O^T += V^T . P^T  (4 d-chunks; A-frag = one b128 from Vt) ----
      #pragma unroll
      for (int ch = 0; ch < 4; ++ch) {
        bf16x8 af = *(const bf16x8*)&Vt[(ch * 16 + c) * 40 + Q * 8];
        f32x4 oo = o[ch];
        #pragma unroll
        for (int t2 = 0; t2 < 4; ++t2) oo[t2] *= alpha;
        o[ch] = __builtin_amdgcn_mfma_f32_16x16x32_bf16(af, pb, oo, 0, 0, 0);
      }
    }
  }

  // ---- epilogue: O[q][d] = O^T[d][q] / l ----
  if (nqw > 0 && c < nqw) {
    const float invl = 1.f / l_run;
    const int tok = r + (q0 + qb + c) * p;
    unsigned int* dst =
        (unsigned int*)(ao + (size_t)(b * T_ + tok) * D_ + h * HD_);
    #pragma unroll
    for (int ch = 0; ch < 4; ++ch)
      #pragma unroll
      for (int rp = 0; rp < 2; ++rp) {
        const int dhalf = ch * 16 + Q * 4 + rp * 2;   // even
        dst[dhalf >> 1] =
            pack2bf(o[ch][rp * 2] * invl, o[ch][rp * 2 + 1] * invl);
      }
  }
}

// ---------------------------------------------------------------------------
extern "C" void kernel_launch(void* const* d_in, const int* in_sizes, int n_in,
                              void* d_out, int out_size, void* d_ws, size_t ws_size,
                              hipStream_t stream) {
  const float* x      = (const float*)d_in[0];   // (B,T,D)
  const int*   period = (const int*)  d_in[1];   // (B,H)
  const float* w_qkv  = (const float*)d_in[2];   // (3D, D)
  const float* b_qkv  = (const float*)d_in[3];   // (3D,)
  const float* w_out  = (const float*)d_in[4];   // (D, D)
  const float* b_out  = (const float*)d_in[5];   // (D,)
  float* out = (float*)d_out;                    // (B,T,D)

  const int M = B_ * T_;                         // 4096

  // ws layout (MB): xb[0,4) wqb[4,5.5) wob[5.5,6) qkvb[6,18)
  char* ws = (char*)d_ws;
  unsigned short* xb   = (unsigned short*)(ws);
  unsigned short* wqb  = (unsigned short*)(ws + (size_t)M * D_ * 2);
  unsigned short* wob  = (unsigned short*)(ws + (size_t)M * D_ * 2
                                              + (size_t)QKVS * D_ * 2);
  unsigned short* qkvb = (unsigned short*)(ws + (size_t)M * D_ * 2
                                              + (size_t)QKVS * D_ * 2
                                              + (size_t)D_ * D_ * 2);
  unsigned short* aob  = xb;   // alias: x_bf16 dead after GEMM1

  // fused input casts
  {
    const int n4 = (M * D_ + QKVS * D_ + D_ * D_) / 4;
    cast_all<<<dim3((n4 + 255) / 256), dim3(256), 0, stream>>>(
        x, w_qkv, w_out, xb, wqb, wob);
  }

  // 1) QKV projection -> bf16 token-major qkvb.
  //    LDS-free direct GEMM, 64x128 blocks: grid (12, 64) = 768 = 3/CU.
  gemm_nt_direct<1, 16><<<dim3(QKVS / 128, M / 64), dim3(256), 0, stream>>>(
      xb, wqb, b_qkv, qkvb, M, QKVS, D_);

  // 2) residue-class flash attention (64-query stripes) -> aob (bf16)
  attn_flash2<<<dim3(16, 63), dim3(256), 0, stream>>>(qkvb, period, aob);

  // 3) output projection -> fp32 out. grid (4, 64) = 256 = 1/CU.
  gemm_nt_direct<0, 16><<<dim3(D_ / 128, M / 64), dim3(256), 0, stream>>>(
      aob, wob, b_out, out, M, D_, D_);
}

// Round 9
// 113.368 us; speedup vs baseline: 1.1959x; 1.1959x over previous
//
#include <hip/hip_runtime.h>
#include <math.h>

#define B_  2
#define T_  2048
#define D_  512
#define H_  8
#define HD_ 64
#define QKVS (3*D_)   // 1536

typedef __bf16 bf16x8 __attribute__((ext_vector_type(8)));
typedef float  f32x4  __attribute__((ext_vector_type(4)));

__device__ inline unsigned short f2bf(float f) {   // RN-even fp32->bf16
  unsigned int u = __float_as_uint(f);
  return (unsigned short)((u + 0x7FFFu + ((u >> 16) & 1u)) >> 16);
}
__device__ inline unsigned int pack2bf(float lo, float hi) {
  return (unsigned int)f2bf(lo) | ((unsigned int)f2bf(hi) << 16);
}

// ---------------------------------------------------------------------------
// Fused cast fp32 -> bf16 for x, w_qkv, w_out in one launch (float4 units).
// ---------------------------------------------------------------------------
__global__ void cast_all(const float* __restrict__ x,
                         const float* __restrict__ wq,
                         const float* __restrict__ wo,
                         unsigned short* __restrict__ xb,
                         unsigned short* __restrict__ wqb,
                         unsigned short* __restrict__ wob) {
  const int n_x  = (B_ * T_ * D_) / 4;
  const int n_wq = (QKVS * D_) / 4;
  const int n_wo = (D_ * D_) / 4;
  int i = blockIdx.x * blockDim.x + threadIdx.x;
  const float* src; unsigned short* dst; int off;
  if (i < n_x)                    { src = x;  dst = xb;  off = i; }
  else if (i < n_x + n_wq)        { src = wq; dst = wqb; off = i - n_x; }
  else if (i < n_x + n_wq + n_wo) { src = wo; dst = wob; off = i - n_x - n_wq; }
  else return;
  float4 v = ((const float4*)src)[off];
  ushort4 o;
  o.x = f2bf(v.x); o.y = f2bf(v.y); o.z = f2bf(v.z); o.w = f2bf(v.w);
  ((ushort4*)dst)[off] = o;
}

// ---------------------------------------------------------------------------
// MFMA bf16 GEMM (NT), 128x64 tile, BK=32: 4 waves, each 64x32 = 4x2 accs.
// Used for out-projection (grid 256 = 1 block/CU).
// ---------------------------------------------------------------------------
template<int BF16OUT>
__global__ __launch_bounds__(256)
void gemm_nt_mfma(const unsigned short* __restrict__ A,
                  const unsigned short* __restrict__ Bw,
                  const float* __restrict__ bias, void* __restrict__ Cv,
                  int M, int N, int K) {
  __shared__ short Asd[128 * 32];
  __shared__ short Bsd[64 * 32];

  const int tid = threadIdx.x;
  const int w   = tid >> 6;
  const int l   = tid & 63;
  const int wr  = w >> 1;
  const int wc  = w & 1;
  const int q   = l >> 4;
  const int ml  = l & 15;
  const int arow = l >> 2;
  const int kch  = (l & 3) * 8;

  const int rowbase = blockIdx.y * 128;
  const int colbase = blockIdx.x * 64;

  f32x4 acc[4][2] = {};

  for (int k0 = 0; k0 < K; k0 += 32) {
    __syncthreads();
    #pragma unroll
    for (int s = 0; s < 2; ++s) {
      const unsigned short* g =
          A + (size_t)(rowbase + s * 64 + w * 16 + arow) * K + k0 + kch;
      __builtin_amdgcn_global_load_lds(
          (const __attribute__((address_space(1))) void*)g,
          (__attribute__((address_space(3))) void*)&Asd[s * 2048 + w * 512],
          16, 0, 0);
    }
    {
      const unsigned short* g =
          Bw + (size_t)(colbase + w * 16 + arow) * K + k0 + kch;
      __builtin_amdgcn_global_load_lds(
          (const __attribute__((address_space(1))) void*)g,
          (__attribute__((address_space(3))) void*)&Bsd[w * 512], 16, 0, 0);
    }
    __syncthreads();

    bf16x8 af[4], bfr[2];
    #pragma unroll
    for (int mi = 0; mi < 4; ++mi)
      af[mi] = *(const bf16x8*)&Asd[(wr * 64 + mi * 16 + ml) * 32 + q * 8];
    #pragma unroll
    for (int ni = 0; ni < 2; ++ni)
      bfr[ni] = *(const bf16x8*)&Bsd[(wc * 32 + ni * 16 + ml) * 32 + q * 8];
    #pragma unroll
    for (int mi = 0; mi < 4; ++mi)
      #pragma unroll
      for (int ni = 0; ni < 2; ++ni)
        acc[mi][ni] = __builtin_amdgcn_mfma_f32_16x16x32_bf16(
            af[mi], bfr[ni], acc[mi][ni], 0, 0, 0);
  }

  #pragma unroll
  for (int mi = 0; mi < 4; ++mi) {
    #pragma unroll
    for (int ni = 0; ni < 2; ++ni) {
      const int col = colbase + wc * 32 + ni * 16 + ml;
      const float bv = bias[col];
      #pragma unroll
      for (int r = 0; r < 4; ++r) {
        const int row = rowbase + wr * 64 + mi * 16 + q * 4 + r;
        const float val = acc[mi][ni][r] + bv;
        if (BF16OUT)
          ((unsigned short*)Cv)[(size_t)row * N + col] = f2bf(val);
        else
          ((float*)Cv)[(size_t)row * N + col] = val;
      }
    }
  }
}

// ---------------------------------------------------------------------------
// MFMA bf16 GEMM (NT), 128x128 tile: 4 waves (2x2), each 64x64 = 4x4 accs.
// Used for QKV projection (grid 384).
// ---------------------------------------------------------------------------
template<int BF16OUT>
__global__ __launch_bounds__(256)
void gemm_nt_mfma128(const unsigned short* __restrict__ A,
                     const unsigned short* __restrict__ Bw,
                     const float* __restrict__ bias, void* __restrict__ Cv,
                     int M, int N, int K) {
  __shared__ short Asd[128 * 32];   // 8 KB
  __shared__ short Bsd[128 * 32];   // 8 KB

  const int tid = threadIdx.x;
  const int w   = tid >> 6;
  const int l   = tid & 63;
  const int wr  = w >> 1;
  const int wc  = w & 1;
  const int q   = l >> 4;
  const int ml  = l & 15;
  const int arow = l >> 2;
  const int kch  = (l & 3) * 8;

  const int rowbase = blockIdx.y * 128;
  const int colbase = blockIdx.x * 128;

  f32x4 acc[4][4] = {};

  for (int k0 = 0; k0 < K; k0 += 32) {
    __syncthreads();
    #pragma unroll
    for (int s = 0; s < 2; ++s) {
      const unsigned short* ga =
          A + (size_t)(rowbase + s * 64 + w * 16 + arow) * K + k0 + kch;
      __builtin_amdgcn_global_load_lds(
          (const __attribute__((address_space(1))) void*)ga,
          (__attribute__((address_space(3))) void*)&Asd[s * 2048 + w * 512],
          16, 0, 0);
      const unsigned short* gb =
          Bw + (size_t)(colbase + s * 64 + w * 16 + arow) * K + k0 + kch;
      __builtin_amdgcn_global_load_lds(
          (const __attribute__((address_space(1))) void*)gb,
          (__attribute__((address_space(3))) void*)&Bsd[s * 2048 + w * 512],
          16, 0, 0);
    }
    __syncthreads();

    bf16x8 af[4], bfr[4];
    #pragma unroll
    for (int mi = 0; mi < 4; ++mi)
      af[mi] = *(const bf16x8*)&Asd[(wr * 64 + mi * 16 + ml) * 32 + q * 8];
    #pragma unroll
    for (int ni = 0; ni < 4; ++ni)
      bfr[ni] = *(const bf16x8*)&Bsd[(wc * 64 + ni * 16 + ml) * 32 + q * 8];
    #pragma unroll
    for (int mi = 0; mi < 4; ++mi)
      #pragma unroll
      for (int ni = 0; ni < 4; ++ni)
        acc[mi][ni] = __builtin_amdgcn_mfma_f32_16x16x32_bf16(
            af[mi], bfr[ni], acc[mi][ni], 0, 0, 0);
  }

  #pragma unroll
  for (int mi = 0; mi < 4; ++mi) {
    #pragma unroll
    for (int ni = 0; ni < 4; ++ni) {
      const int col = colbase + wc * 64 + ni * 16 + ml;
      const float bv = bias[col];
      #pragma unroll
      for (int r = 0; r < 4; ++r) {
        const int row = rowbase + wr * 64 + mi * 16 + q * 4 + r;
        const float val = acc[mi][ni][r] + bv;
        if (BF16OUT)
          ((unsigned short*)Cv)[(size_t)row * N + col] = f2bf(val);
        else
          ((float*)Cv)[(size_t)row * N + col] = val;
      }
    }
  }
}

// ---------------------------------------------------------------------------
// Residue-class flash attention, 64-query stripes (R5 structure) with:
//  (a) heavy-first dispatch: slot = 62 - blockIdx.y (within a head, work
//      rises with slot; heavy blocks must launch first to avoid a tail);
//  (b) software-pipelined staging: tile k+1's global loads issue right after
//      tile k's LDS-valid barrier, hiding L2 latency behind compute.
// ---------------------------------------------------------------------------
__global__ __launch_bounds__(256)
void attn_flash2(const unsigned short* __restrict__ qkv,
                 const int* __restrict__ periods,
                 unsigned short* __restrict__ ao) {
  const int bh = blockIdx.x, slot = 62 - blockIdx.y;   // heavy-first
  int p = periods[bh]; if (p < 1) p = 1;
  const int g  = slot / p;
  const int r  = slot - g * p;
  const int L  = (T_ - 1 - r) / p + 1;   // tokens in this residue class
  const int q0 = g << 6;                 // stripe base (t-space)
  if (q0 >= L) return;
  const int b = bh >> 3, h = bh & 7;
  const int Lrem = L - q0;               // >= 1
  const int Nkb  = min(L, q0 + 64);      // keys needed by the whole block

  const int tid  = threadIdx.x;
  const int w    = tid >> 6;             // wave 0..3
  const int lane = tid & 63;
  const int Q = lane >> 4, c = lane & 15;

  __shared__ __align__(16) unsigned short Qs[64 * 72];  // 9216 B
  __shared__ __align__(16) unsigned short Ks[32 * 72];  // 4608 B
  __shared__ __align__(16) unsigned short Vt[64 * 40];  // 5120 B, [d][key]

  const size_t rowb = (size_t)b * T_ * QKVS + (size_t)h * HD_;

  // ---- stage Q stripe (64 rows x 64 halfs): 32 B per thread ----
  {
    const int u = tid >> 2, ch4 = (tid & 3) * 16;
    const int t = q0 + min(u, Lrem - 1);            // clamp (dup row, masked)
    const unsigned short* gq = qkv + rowb + (size_t)(r + t * p) * QKVS + ch4;
    int4 v0 = ((const int4*)gq)[0];
    int4 v1 = ((const int4*)gq)[1];
    *(int4*)&Qs[u * 72 + ch4 + 0] = v0;
    *(int4*)&Qs[u * 72 + ch4 + 8] = v1;
  }
  __syncthreads();
  bf16x8 qf[2];                          // B-frag: B[k=d=Q*8+j(+32)][n=q=c]
  qf[0] = *(const bf16x8*)&Qs[(w * 16 + c) * 72 + Q * 8];
  qf[1] = *(const bf16x8*)&Qs[(w * 16 + c) * 72 + Q * 8 + 32];

  const int qb      = w * 16;            // wave's query offset in stripe
  const int nqw     = min(16, Lrem - qb);// <=0 -> inactive wave (barriers only)
  const int qglob   = q0 + qb + c;       // this lane's query t-index
  const int mylastk = q0 + qb + 15;      // last key this wave can need

  float m_run = -3.0e38f, l_run = 0.f;
  f32x4 o[4] = {};
  const size_t kb = rowb + D_;
  const size_t vb = rowb + 2 * D_;

  // staging assignments (256 threads)
  const int krow = tid >> 3, koff = (tid & 7) * 8;      // K: 16B/thread
  const int vkey = tid & 31, vd0 = (tid >> 5) * 8;      // V: 16B/thread

  // ---- prefetch tile 0 ----
  int4 kvp, vvp;
  {
    const int tk = min(krow, Nkb - 1);
    const int tv = min(vkey, Nkb - 1);
    kvp = *(const int4*)(qkv + kb + (size_t)(r + tk * p) * QKVS + koff);
    vvp = *(const int4*)(qkv + vb + (size_t)(r + tv * p) * QKVS + vd0);
  }

  for (int k0 = 0; k0 < Nkb; k0 += 32) {
    __syncthreads();                     // prev iter's frag reads complete
    // ---- commit prefetched K (row-major) + V (transposed) tiles ----
    {
      unsigned short vh[8];
      *(int4*)vh = vvp;
      *(int4*)&Ks[krow * 72 + koff] = kvp;
      #pragma unroll
      for (int j = 0; j < 8; ++j)
        Vt[(vd0 + j) * 40 + vkey] = vh[j];
    }
    __syncthreads();                     // LDS valid

    // ---- issue next tile's global loads (latency hides behind compute) ----
    if (k0 + 32 < Nkb) {
      const int tk = min(k0 + 32 + krow, Nkb - 1);
      const int tv = min(k0 + 32 + vkey, Nkb - 1);
      kvp = *(const int4*)(qkv + kb + (size_t)(r + tk * p) * QKVS + koff);
      vvp = *(const int4*)(qkv + vb + (size_t)(r + tv * p) * QKVS + vd0);
    }

    if (nqw > 0 && k0 <= mylastk) {
      // ---- S^T = K . Q^T  (two 16-key M-tiles, K-depth 64) ----
      f32x4 s[2];
      #pragma unroll
      for (int mt = 0; mt < 2; ++mt) {
        bf16x8 a0 = *(const bf16x8*)&Ks[(mt * 16 + c) * 72 + Q * 8];
        bf16x8 a1 = *(const bf16x8*)&Ks[(mt * 16 + c) * 72 + Q * 8 + 32];
        f32x4 acc = {};
        acc = __builtin_amdgcn_mfma_f32_16x16x32_bf16(a0, qf[0], acc, 0, 0, 0);
        acc = __builtin_amdgcn_mfma_f32_16x16x32_bf16(a1, qf[1], acc, 0, 0, 0);
        s[mt] = acc;
      }

      // ---- scale + causal mask + online softmax (per col q=c) ----
      float pvv[8];
      float tmax = -3.0e38f;
      #pragma unroll
      for (int mt = 0; mt < 2; ++mt)
        #pragma unroll
        for (int rg = 0; rg < 4; ++rg) {
          const int kk = k0 + mt * 16 + Q * 4 + rg;     // key t-index
          float v = s[mt][rg] * 0.125f;                 // 1/sqrt(HD)
          v = (kk <= qglob) ? v : -3.0e38f;
          pvv[mt * 4 + rg] = v;
          tmax = fmaxf(tmax, v);
        }
      tmax = fmaxf(tmax, __shfl_xor(tmax, 16));
      tmax = fmaxf(tmax, __shfl_xor(tmax, 32));
      const float m_new = fmaxf(m_run, tmax);
      const float alpha = __expf(m_run - m_new);
      float tsum = 0.f;
      #pragma unroll
      for (int i = 0; i < 8; ++i) { pvv[i] = __expf(pvv[i] - m_new); tsum += pvv[i]; }
      tsum += __shfl_xor(tsum, 16);
      tsum += __shfl_xor(tsum, 32);
      l_run = l_run * alpha + tsum;
      m_run = m_new;

      // ---- P^T: C-layout -> B-operand layout (8 shfl + 4 selects) ----
      unsigned int pk0[2], pk1[2];
      pk0[0] = pack2bf(pvv[0], pvv[1]); pk0[1] = pack2bf(pvv[2], pvv[3]);
      pk1[0] = pack2bf(pvv[4], pvv[5]); pk1[1] = pack2bf(pvv[6], pvv[7]);
      int dw[4];
      const int sq2 = (Q & 1) << 1;
      #pragma unroll
      for (int d = 0; d < 4; ++d) {
        const int src = ((sq2 + (d >> 1)) << 4) + c;
        const int v0 = __shfl((int)pk0[d & 1], src);
        const int v1 = __shfl((int)pk1[d & 1], src);
        dw[d] = (Q >= 2) ? v1 : v0;
      }
      int4 bi = make_int4(dw[0], dw[1], dw[2], dw[3]);
      bf16x8 pb = *(bf16x8*)&bi;

      // ---- O^T += V^T . P^T  (4 d-chunks; A-frag = one b128 from Vt) ----
      #pragma unroll
      for (int ch = 0; ch < 4; ++ch) {
        bf16x8 af = *(const bf16x8*)&Vt[(ch * 16 + c) * 40 + Q * 8];
        f32x4 oo = o[ch];
        #pragma unroll
        for (int t2 = 0; t2 < 4; ++t2) oo[t2] *= alpha;
        o[ch] = __builtin_amdgcn_mfma_f32_16x16x32_bf16(af, pb, oo, 0, 0, 0);
      }
    }
  }

  // ---- epilogue: O[q][d] = O^T[d][q] / l ----
  if (nqw > 0 && c < nqw) {
    const float invl = 1.f / l_run;
    const int tok = r + (q0 + qb + c) * p;
    unsigned int* dst =
        (unsigned int*)(ao + (size_t)(b * T_ + tok) * D_ + h * HD_);
    #pragma unroll
    for (int ch = 0; ch < 4; ++ch)
      #pragma unroll
      for (int rp = 0; rp < 2; ++rp) {
        const int dhalf = ch * 16 + Q * 4 + rp * 2;   // even
        dst[dhalf >> 1] =
            pack2bf(o[ch][rp * 2] * invl, o[ch][rp * 2 + 1] * invl);
      }
  }
}

// ---------------------------------------------------------------------------
extern "C" void kernel_launch(void* const* d_in, const int* in_sizes, int n_in,
                              void* d_out, int out_size, void* d_ws, size_t ws_size,
                              hipStream_t stream) {
  const float* x      = (const float*)d_in[0];   // (B,T,D)
  const int*   period = (const int*)  d_in[1];   // (B,H)
  const float* w_qkv  = (const float*)d_in[2];   // (3D, D)
  const float* b_qkv  = (const float*)d_in[3];   // (3D,)
  const float* w_out  = (const float*)d_in[4];   // (D, D)
  const float* b_out  = (const float*)d_in[5];   // (D,)
  float* out = (float*)d_out;                    // (B,T,D)

  const int M = B_ * T_;                         // 4096

  // ws layout (MB): xb[0,4) wqb[4,5.5) wob[5.5,6) qkvb[6,18)
  char* ws = (char*)d_ws;
  unsigned short* xb   = (unsigned short*)(ws);
  unsigned short* wqb  = (unsigned short*)(ws + (size_t)M * D_ * 2);
  unsigned short* wob  = (unsigned short*)(ws + (size_t)M * D_ * 2
                                              + (size_t)QKVS * D_ * 2);
  unsigned short* qkvb = (unsigned short*)(ws + (size_t)M * D_ * 2
                                              + (size_t)QKVS * D_ * 2
                                              + (size_t)D_ * D_ * 2);
  unsigned short* aob  = xb;   // alias: x_bf16 dead after GEMM1

  // fused input casts
  {
    const int n4 = (M * D_ + QKVS * D_ + D_ * D_) / 4;
    cast_all<<<dim3((n4 + 255) / 256), dim3(256), 0, stream>>>(
        x, w_qkv, w_out, xb, wqb, wob);
  }

  // 1) QKV projection -> bf16 token-major qkvb (128x128 tile, grid 12x32)
  gemm_nt_mfma128<1><<<dim3(QKVS / 128, M / 128), dim3(256), 0, stream>>>(
      xb, wqb, b_qkv, qkvb, M, QKVS, D_);

  // 2) residue-class flash attention (64-query stripes, heavy-first) -> aob
  attn_flash2<<<dim3(16, 63), dim3(256), 0, stream>>>(qkvb, period, aob);

  // 3) output projection -> fp32 out (128x64 tile, grid 8x32 = 256)
  gemm_nt_mfma<0><<<dim3(D_ / 64, M / 128), dim3(256), 0, stream>>>(
      aob, wob, b_out, out, M, D_, D_);
}

// Round 10
// 107.855 us; speedup vs baseline: 1.2570x; 1.0511x over previous
//
#include <hip/hip_runtime.h>
#include <math.h>

#define B_  2
#define T_  2048
#define D_  512
#define H_  8
#define HD_ 64
#define QKVS (3*D_)   // 1536

typedef __bf16 bf16x8 __attribute__((ext_vector_type(8)));
typedef float  f32x4  __attribute__((ext_vector_type(4)));

__device__ inline unsigned short f2bf(float f) {   // RN-even fp32->bf16
  unsigned int u = __float_as_uint(f);
  return (unsigned short)((u + 0x7FFFu + ((u >> 16) & 1u)) >> 16);
}
__device__ inline unsigned int pack2bf(float lo, float hi) {
  return (unsigned int)f2bf(lo) | ((unsigned int)f2bf(hi) << 16);
}

// ---------------------------------------------------------------------------
// Fused cast fp32 -> bf16 for x, w_qkv, w_out in one launch (float4 units).
// ---------------------------------------------------------------------------
__global__ void cast_all(const float* __restrict__ x,
                         const float* __restrict__ wq,
                         const float* __restrict__ wo,
                         unsigned short* __restrict__ xb,
                         unsigned short* __restrict__ wqb,
                         unsigned short* __restrict__ wob) {
  const int n_x  = (B_ * T_ * D_) / 4;
  const int n_wq = (QKVS * D_) / 4;
  const int n_wo = (D_ * D_) / 4;
  int i = blockIdx.x * blockDim.x + threadIdx.x;
  const float* src; unsigned short* dst; int off;
  if (i < n_x)                    { src = x;  dst = xb;  off = i; }
  else if (i < n_x + n_wq)        { src = wq; dst = wqb; off = i - n_x; }
  else if (i < n_x + n_wq + n_wo) { src = wo; dst = wob; off = i - n_x - n_wq; }
  else return;
  float4 v = ((const float4*)src)[off];
  ushort4 o;
  o.x = f2bf(v.x); o.y = f2bf(v.y); o.z = f2bf(v.z); o.w = f2bf(v.w);
  ((ushort4*)dst)[off] = o;
}

// ---------------------------------------------------------------------------
// MFMA bf16 GEMM (NT), 128x64 tile, BK=64 via TWO 32-K panels per barrier
// round: both panels staged back-to-back with global_load_lds (per-panel
// lane mapping identical to the proven BK=32 scheme), ONE barrier pair per
// 64 K -> 8 rounds for K=512 (half the vmcnt(0) drains of BK=32).
// 4 waves, each 64x32 = 4x2 accs; 16 MFMAs/wave/round.
// ---------------------------------------------------------------------------
template<int BF16OUT>
__global__ __launch_bounds__(256, 3)
void gemm_nt_bk64(const unsigned short* __restrict__ A,
                  const unsigned short* __restrict__ Bw,
                  const float* __restrict__ bias, void* __restrict__ Cv,
                  int M, int N, int K) {
  __shared__ short Asd[2][128 * 32];   // 2 x 8 KB
  __shared__ short Bsd[2][64 * 32];    // 2 x 4 KB

  const int tid = threadIdx.x;
  const int w   = tid >> 6;
  const int l   = tid & 63;
  const int wr  = w >> 1;
  const int wc  = w & 1;
  const int q   = l >> 4;
  const int ml  = l & 15;
  const int arow = l >> 2;
  const int kch  = (l & 3) * 8;

  const int rowbase = blockIdx.y * 128;
  const int colbase = blockIdx.x * 64;

  f32x4 acc[4][2] = {};

  for (int k0 = 0; k0 < K; k0 += 64) {
    __syncthreads();
    #pragma unroll
    for (int pnl = 0; pnl < 2; ++pnl) {
      const int kp = k0 + pnl * 32;
      #pragma unroll
      for (int s = 0; s < 2; ++s) {
        const unsigned short* g =
            A + (size_t)(rowbase + s * 64 + w * 16 + arow) * K + kp + kch;
        __builtin_amdgcn_global_load_lds(
            (const __attribute__((address_space(1))) void*)g,
            (__attribute__((address_space(3))) void*)
                &Asd[pnl][s * 2048 + w * 512], 16, 0, 0);
      }
      const unsigned short* g =
          Bw + (size_t)(colbase + w * 16 + arow) * K + kp + kch;
      __builtin_amdgcn_global_load_lds(
          (const __attribute__((address_space(1))) void*)g,
          (__attribute__((address_space(3))) void*)&Bsd[pnl][w * 512],
          16, 0, 0);
    }
    __syncthreads();

    #pragma unroll
    for (int pnl = 0; pnl < 2; ++pnl) {
      bf16x8 af[4], bfr[2];
      #pragma unroll
      for (int mi = 0; mi < 4; ++mi)
        af[mi] = *(const bf16x8*)&Asd[pnl][(wr * 64 + mi * 16 + ml) * 32 + q * 8];
      #pragma unroll
      for (int ni = 0; ni < 2; ++ni)
        bfr[ni] = *(const bf16x8*)&Bsd[pnl][(wc * 32 + ni * 16 + ml) * 32 + q * 8];
      #pragma unroll
      for (int mi = 0; mi < 4; ++mi)
        #pragma unroll
        for (int ni = 0; ni < 2; ++ni)
          acc[mi][ni] = __builtin_amdgcn_mfma_f32_16x16x32_bf16(
              af[mi], bfr[ni], acc[mi][ni], 0, 0, 0);
    }
  }

  #pragma unroll
  for (int mi = 0; mi < 4; ++mi) {
    #pragma unroll
    for (int ni = 0; ni < 2; ++ni) {
      const int col = colbase + wc * 32 + ni * 16 + ml;
      const float bv = bias[col];
      #pragma unroll
      for (int r = 0; r < 4; ++r) {
        const int row = rowbase + wr * 64 + mi * 16 + q * 4 + r;
        const float val = acc[mi][ni][r] + bv;
        if (BF16OUT)
          ((unsigned short*)Cv)[(size_t)row * N + col] = f2bf(val);
        else
          ((float*)Cv)[(size_t)row * N + col] = val;
      }
    }
  }
}

// ---------------------------------------------------------------------------
// Residue-class flash attention, 64-query stripes, 64-KEY rounds:
//  - heavy-first dispatch (slot = 62 - blockIdx.y);
//  - prefetch pipeline (next round's global loads issue after LDS-valid);
//  - per-16-key-tile skip keeps light waves cheap;
//  - half the barrier rounds of the 32-key version (critical p=1 block:
//    32 rounds instead of 64).
// LDS: Qs 9.2K + Ks 9.2K + Vt 9.2K = 27.6 KB (stride 72 -> 2-way = free).
// ---------------------------------------------------------------------------
__global__ __launch_bounds__(256)
void attn_flash4(const unsigned short* __restrict__ qkv,
                 const int* __restrict__ periods,
                 unsigned short* __restrict__ ao) {
  const int bh = blockIdx.x, slot = 62 - blockIdx.y;   // heavy-first
  int p = periods[bh]; if (p < 1) p = 1;
  const int g  = slot / p;
  const int r  = slot - g * p;
  const int L  = (T_ - 1 - r) / p + 1;   // tokens in this residue class
  const int q0 = g << 6;                 // stripe base (t-space)
  if (q0 >= L) return;
  const int b = bh >> 3, h = bh & 7;
  const int Lrem = L - q0;               // >= 1
  const int Nkb  = min(L, q0 + 64);      // keys needed by the whole block

  const int tid  = threadIdx.x;
  const int w    = tid >> 6;             // wave 0..3
  const int lane = tid & 63;
  const int Q = lane >> 4, c = lane & 15;

  __shared__ __align__(16) unsigned short Qs[64 * 72];  // 9216 B
  __shared__ __align__(16) unsigned short Ks[64 * 72];  // 9216 B
  __shared__ __align__(16) unsigned short Vt[64 * 72];  // 9216 B, [d][key]

  const size_t rowb = (size_t)b * T_ * QKVS + (size_t)h * HD_;

  // ---- stage Q stripe (64 rows x 64 halfs): 32 B per thread ----
  {
    const int u = tid >> 2, ch4 = (tid & 3) * 16;
    const int t = q0 + min(u, Lrem - 1);            // clamp (dup row, masked)
    const unsigned short* gq = qkv + rowb + (size_t)(r + t * p) * QKVS + ch4;
    int4 v0 = ((const int4*)gq)[0];
    int4 v1 = ((const int4*)gq)[1];
    *(int4*)&Qs[u * 72 + ch4 + 0] = v0;
    *(int4*)&Qs[u * 72 + ch4 + 8] = v1;
  }
  __syncthreads();
  bf16x8 qf[2];                          // B-frag: B[k=d=Q*8+j(+32)][n=q=c]
  qf[0] = *(const bf16x8*)&Qs[(w * 16 + c) * 72 + Q * 8];
  qf[1] = *(const bf16x8*)&Qs[(w * 16 + c) * 72 + Q * 8 + 32];

  const int qb      = w * 16;            // wave's query offset in stripe
  const int nqw     = min(16, Lrem - qb);// <=0 -> inactive wave (barriers only)
  const int qglob   = q0 + qb + c;       // this lane's query t-index
  const int mylastk = q0 + qb + 15;      // last key this wave can need

  float m_run = -3.0e38f, l_run = 0.f;
  f32x4 o[4] = {};
  const size_t kb = rowb + D_;
  const size_t vb = rowb + 2 * D_;

  // staging assignments (256 threads, 64-key tiles)
  const int krow = tid >> 2, koff = (tid & 3) * 16;     // K: 2x16B/thread
  const int vkey = tid & 63, vd0 = (tid >> 6) * 8;      // V: 2x16B/thread

  // ---- prefetch round 0 ----
  int4 kp0, kp1, vp0, vp1;
  {
    const int tk = min(krow, Nkb - 1);
    const int tv = min(vkey, Nkb - 1);
    const unsigned short* gk = qkv + kb + (size_t)(r + tk * p) * QKVS + koff;
    const unsigned short* gv = qkv + vb + (size_t)(r + tv * p) * QKVS;
    kp0 = ((const int4*)gk)[0];
    kp1 = ((const int4*)gk)[1];
    vp0 = *(const int4*)(gv + vd0);
    vp1 = *(const int4*)(gv + vd0 + 32);
  }

  for (int k0 = 0; k0 < Nkb; k0 += 64) {
    __syncthreads();                     // prev round's frag reads complete
    // ---- commit prefetched K (row-major) + V (transposed) ----
    {
      *(int4*)&Ks[krow * 72 + koff + 0] = kp0;
      *(int4*)&Ks[krow * 72 + koff + 8] = kp1;
      unsigned short vh0[8], vh1[8];
      *(int4*)vh0 = vp0;
      *(int4*)vh1 = vp1;
      #pragma unroll
      for (int j = 0; j < 8; ++j) {
        Vt[(vd0 + j) * 72 + vkey]      = vh0[j];
        Vt[(vd0 + 32 + j) * 72 + vkey] = vh1[j];
      }
    }
    __syncthreads();                     // LDS valid

    // ---- issue next round's global loads (hide behind compute) ----
    if (k0 + 64 < Nkb) {
      const int tk = min(k0 + 64 + krow, Nkb - 1);
      const int tv = min(k0 + 64 + vkey, Nkb - 1);
      const unsigned short* gk = qkv + kb + (size_t)(r + tk * p) * QKVS + koff;
      const unsigned short* gv = qkv + vb + (size_t)(r + tv * p) * QKVS;
      kp0 = ((const int4*)gk)[0];
      kp1 = ((const int4*)gk)[1];
      vp0 = *(const int4*)(gv + vd0);
      vp1 = *(const int4*)(gv + vd0 + 32);
    }

    if (nqw > 0 && k0 <= mylastk) {
      // ---- S^T tiles (4 x 16 keys), per-tile skip ----
      float pvv[16];
      float tmax = -3.0e38f;
      #pragma unroll
      for (int mt = 0; mt < 4; ++mt) {
        if (k0 + mt * 16 <= mylastk) {
          bf16x8 a0 = *(const bf16x8*)&Ks[(mt * 16 + c) * 72 + Q * 8];
          bf16x8 a1 = *(const bf16x8*)&Ks[(mt * 16 + c) * 72 + Q * 8 + 32];
          f32x4 s = {};
          s = __builtin_amdgcn_mfma_f32_16x16x32_bf16(a0, qf[0], s, 0, 0, 0);
          s = __builtin_amdgcn_mfma_f32_16x16x32_bf16(a1, qf[1], s, 0, 0, 0);
          #pragma unroll
          for (int rg = 0; rg < 4; ++rg) {
            const int kk = k0 + mt * 16 + Q * 4 + rg;   // key t-index
            float v = s[rg] * 0.125f;                   // 1/sqrt(HD)
            v = (kk <= qglob) ? v : -3.0e38f;
            pvv[mt * 4 + rg] = v;
            tmax = fmaxf(tmax, v);
          }
        } else {
          #pragma unroll
          for (int rg = 0; rg < 4; ++rg) pvv[mt * 4 + rg] = -3.0e38f;
        }
      }

      // ---- online softmax per column (q = c) ----
      tmax = fmaxf(tmax, __shfl_xor(tmax, 16));
      tmax = fmaxf(tmax, __shfl_xor(tmax, 32));
      const float m_new = fmaxf(m_run, tmax);
      const float alpha = __expf(m_run - m_new);
      float tsum = 0.f;
      #pragma unroll
      for (int i = 0; i < 16; ++i) {
        pvv[i] = __expf(pvv[i] - m_new);
        tsum += pvv[i];
      }
      tsum += __shfl_xor(tsum, 16);
      tsum += __shfl_xor(tsum, 32);
      l_run = l_run * alpha + tsum;
      m_run = m_new;

      // ---- P^T -> B-operand frags per 32-key chunk ----
      bf16x8 pb[2];
      const int sq2 = (Q & 1) << 1;
      #pragma unroll
      for (int kc = 0; kc < 2; ++kc) {
        unsigned int pk0[2], pk1[2];
        pk0[0] = pack2bf(pvv[kc * 8 + 0], pvv[kc * 8 + 1]);
        pk0[1] = pack2bf(pvv[kc * 8 + 2], pvv[kc * 8 + 3]);
        pk1[0] = pack2bf(pvv[kc * 8 + 4], pvv[kc * 8 + 5]);
        pk1[1] = pack2bf(pvv[kc * 8 + 6], pvv[kc * 8 + 7]);
        int dw[4];
        #pragma unroll
        for (int d = 0; d < 4; ++d) {
          const int src = ((sq2 + (d >> 1)) << 4) + c;
          const int v0 = __shfl((int)pk0[d & 1], src);
          const int v1 = __shfl((int)pk1[d & 1], src);
          dw[d] = (Q >= 2) ? v1 : v0;
        }
        int4 bi = make_int4(dw[0], dw[1], dw[2], dw[3]);
        pb[kc] = *(bf16x8*)&bi;
      }

      // ---- O^T += V^T . P^T  (2 key-chunks x 4 d-chunks) ----
      #pragma unroll
      for (int ch = 0; ch < 4; ++ch)
        #pragma unroll
        for (int t2 = 0; t2 < 4; ++t2) o[ch][t2] *= alpha;
      #pragma unroll
      for (int kc = 0; kc < 2; ++kc) {
        if (k0 + kc * 32 <= mylastk) {
          #pragma unroll
          for (int ch = 0; ch < 4; ++ch) {
            bf16x8 af =
                *(const bf16x8*)&Vt[(ch * 16 + c) * 72 + kc * 32 + Q * 8];
            o[ch] = __builtin_amdgcn_mfma_f32_16x16x32_bf16(af, pb[kc], o[ch],
                                                            0, 0, 0);
          }
        }
      }
    }
  }

  // ---- epilogue: O[q][d] = O^T[d][q] / l ----
  if (nqw > 0 && c < nqw) {
    const float invl = 1.f / l_run;
    const int tok = r + (q0 + qb + c) * p;
    unsigned int* dst =
        (unsigned int*)(ao + (size_t)(b * T_ + tok) * D_ + h * HD_);
    #pragma unroll
    for (int ch = 0; ch < 4; ++ch)
      #pragma unroll
      for (int rp = 0; rp < 2; ++rp) {
        const int dhalf = ch * 16 + Q * 4 + rp * 2;   // even
        dst[dhalf >> 1] =
            pack2bf(o[ch][rp * 2] * invl, o[ch][rp * 2 + 1] * invl);
      }
  }
}

// ---------------------------------------------------------------------------
extern "C" void kernel_launch(void* const* d_in, const int* in_sizes, int n_in,
                              void* d_out, int out_size, void* d_ws, size_t ws_size,
                              hipStream_t stream) {
  const float* x      = (const float*)d_in[0];   // (B,T,D)
  const int*   period = (const int*)  d_in[1];   // (B,H)
  const float* w_qkv  = (const float*)d_in[2];   // (3D, D)
  const float* b_qkv  = (const float*)d_in[3];   // (3D,)
  const float* w_out  = (const float*)d_in[4];   // (D, D)
  const float* b_out  = (const float*)d_in[5];   // (D,)
  float* out = (float*)d_out;                    // (B,T,D)

  const int M = B_ * T_;                         // 4096

  // ws layout (MB): xb[0,4) wqb[4,5.5) wob[5.5,6) qkvb[6,18)
  char* ws = (char*)d_ws;
  unsigned short* xb   = (unsigned short*)(ws);
  unsigned short* wqb  = (unsigned short*)(ws + (size_t)M * D_ * 2);
  unsigned short* wob  = (unsigned short*)(ws + (size_t)M * D_ * 2
                                              + (size_t)QKVS * D_ * 2);
  unsigned short* qkvb = (unsigned short*)(ws + (size_t)M * D_ * 2
                                              + (size_t)QKVS * D_ * 2
                                              + (size_t)D_ * D_ * 2);
  unsigned short* aob  = xb;   // alias: x_bf16 dead after GEMM1

  // fused input casts
  {
    const int n4 = (M * D_ + QKVS * D_ + D_ * D_) / 4;
    cast_all<<<dim3((n4 + 255) / 256), dim3(256), 0, stream>>>(
        x, w_qkv, w_out, xb, wqb, wob);
  }

  // 1) QKV projection -> bf16 token-major qkvb (128x64 tile, BK=64, grid 768)
  gemm_nt_bk64<1><<<dim3(QKVS / 64, M / 128), dim3(256), 0, stream>>>(
      xb, wqb, b_qkv, qkvb, M, QKVS, D_);

  // 2) residue-class flash attention (64-query stripes, 64-key rounds) -> aob
  attn_flash4<<<dim3(16, 63), dim3(256), 0, stream>>>(qkvb, period, aob);

  // 3) output projection -> fp32 out (128x64 tile, BK=64, grid 256)
  gemm_nt_bk64<0><<<dim3(D_ / 64, M / 128), dim3(256), 0, stream>>>(
      aob, wob, b_out, out, M, D_, D_);
}

// Round 11
// 107.600 us; speedup vs baseline: 1.2600x; 1.0024x over previous
//
#include <hip/hip_runtime.h>
#include <math.h>

#define B_  2
#define T_  2048
#define D_  512
#define H_  8
#define HD_ 64
#define QKVS (3*D_)   // 1536

typedef __bf16 bf16x8 __attribute__((ext_vector_type(8)));
typedef float  f32x4  __attribute__((ext_vector_type(4)));

__device__ inline unsigned short f2bf(float f) {   // RN-even fp32->bf16
  unsigned int u = __float_as_uint(f);
  return (unsigned short)((u + 0x7FFFu + ((u >> 16) & 1u)) >> 16);
}
__device__ inline unsigned int pack2bf(float lo, float hi) {
  return (unsigned int)f2bf(lo) | ((unsigned int)f2bf(hi) << 16);
}

// ---------------------------------------------------------------------------
// Fused cast fp32 -> bf16 for x, w_qkv, w_out in one launch (float4 units).
// ---------------------------------------------------------------------------
__global__ void cast_all(const float* __restrict__ x,
                         const float* __restrict__ wq,
                         const float* __restrict__ wo,
                         unsigned short* __restrict__ xb,
                         unsigned short* __restrict__ wqb,
                         unsigned short* __restrict__ wob) {
  const int n_x  = (B_ * T_ * D_) / 4;
  const int n_wq = (QKVS * D_) / 4;
  const int n_wo = (D_ * D_) / 4;
  int i = blockIdx.x * blockDim.x + threadIdx.x;
  const float* src; unsigned short* dst; int off;
  if (i < n_x)                    { src = x;  dst = xb;  off = i; }
  else if (i < n_x + n_wq)        { src = wq; dst = wqb; off = i - n_x; }
  else if (i < n_x + n_wq + n_wo) { src = wo; dst = wob; off = i - n_x - n_wq; }
  else return;
  float4 v = ((const float4*)src)[off];
  ushort4 o;
  o.x = f2bf(v.x); o.y = f2bf(v.y); o.z = f2bf(v.z); o.w = f2bf(v.w);
  ((ushort4*)dst)[off] = o;
}

// ---------------------------------------------------------------------------
// MFMA bf16 GEMM (NT), 128x64 tile, BK=128 via FOUR 32-K panels per barrier
// round (per-panel global_load_lds lane mapping identical to the proven
// BK=32 scheme). ONE barrier pair per 128 K -> 4 rounds for K=512.
// LDS = 4 x 12 KB = 48 KB -> still 3 blocks/CU (m132's cliff was 64 KB at
// tile 128x128; this keeps the 128x64 tile). 4 waves, 4x2 accs each.
// ---------------------------------------------------------------------------
template<int BF16OUT>
__global__ __launch_bounds__(256, 3)
void gemm_nt_bk128(const unsigned short* __restrict__ A,
                   const unsigned short* __restrict__ Bw,
                   const float* __restrict__ bias, void* __restrict__ Cv,
                   int M, int N, int K) {
  __shared__ short Asd[4][128 * 32];   // 4 x 8 KB
  __shared__ short Bsd[4][64 * 32];    // 4 x 4 KB

  const int tid = threadIdx.x;
  const int w   = tid >> 6;
  const int l   = tid & 63;
  const int wr  = w >> 1;
  const int wc  = w & 1;
  const int q   = l >> 4;
  const int ml  = l & 15;
  const int arow = l >> 2;
  const int kch  = (l & 3) * 8;

  const int rowbase = blockIdx.y * 128;
  const int colbase = blockIdx.x * 64;

  f32x4 acc[4][2] = {};

  for (int k0 = 0; k0 < K; k0 += 128) {
    __syncthreads();
    #pragma unroll
    for (int pnl = 0; pnl < 4; ++pnl) {
      const int kp = k0 + pnl * 32;
      #pragma unroll
      for (int s = 0; s < 2; ++s) {
        const unsigned short* g =
            A + (size_t)(rowbase + s * 64 + w * 16 + arow) * K + kp + kch;
        __builtin_amdgcn_global_load_lds(
            (const __attribute__((address_space(1))) void*)g,
            (__attribute__((address_space(3))) void*)
                &Asd[pnl][s * 2048 + w * 512], 16, 0, 0);
      }
      const unsigned short* g =
          Bw + (size_t)(colbase + w * 16 + arow) * K + kp + kch;
      __builtin_amdgcn_global_load_lds(
          (const __attribute__((address_space(1))) void*)g,
          (__attribute__((address_space(3))) void*)&Bsd[pnl][w * 512],
          16, 0, 0);
    }
    __syncthreads();

    #pragma unroll
    for (int pnl = 0; pnl < 4; ++pnl) {
      bf16x8 af[4], bfr[2];
      #pragma unroll
      for (int mi = 0; mi < 4; ++mi)
        af[mi] = *(const bf16x8*)&Asd[pnl][(wr * 64 + mi * 16 + ml) * 32 + q * 8];
      #pragma unroll
      for (int ni = 0; ni < 2; ++ni)
        bfr[ni] = *(const bf16x8*)&Bsd[pnl][(wc * 32 + ni * 16 + ml) * 32 + q * 8];
      #pragma unroll
      for (int mi = 0; mi < 4; ++mi)
        #pragma unroll
        for (int ni = 0; ni < 2; ++ni)
          acc[mi][ni] = __builtin_amdgcn_mfma_f32_16x16x32_bf16(
              af[mi], bfr[ni], acc[mi][ni], 0, 0, 0);
    }
  }

  #pragma unroll
  for (int mi = 0; mi < 4; ++mi) {
    #pragma unroll
    for (int ni = 0; ni < 2; ++ni) {
      const int col = colbase + wc * 32 + ni * 16 + ml;
      const float bv = bias[col];
      #pragma unroll
      for (int r = 0; r < 4; ++r) {
        const int row = rowbase + wr * 64 + mi * 16 + q * 4 + r;
        const float val = acc[mi][ni][r] + bv;
        if (BF16OUT)
          ((unsigned short*)Cv)[(size_t)row * N + col] = f2bf(val);
        else
          ((float*)Cv)[(size_t)row * N + col] = val;
      }
    }
  }
}

// ---------------------------------------------------------------------------
// Residue-class flash attention, 64-query stripes, 64-key rounds (R10 exact):
// heavy-first dispatch, prefetch pipeline, per-16-key-tile skip.
// ---------------------------------------------------------------------------
__global__ __launch_bounds__(256)
void attn_flash4(const unsigned short* __restrict__ qkv,
                 const int* __restrict__ periods,
                 unsigned short* __restrict__ ao) {
  const int bh = blockIdx.x, slot = 62 - blockIdx.y;   // heavy-first
  int p = periods[bh]; if (p < 1) p = 1;
  const int g  = slot / p;
  const int r  = slot - g * p;
  const int L  = (T_ - 1 - r) / p + 1;   // tokens in this residue class
  const int q0 = g << 6;                 // stripe base (t-space)
  if (q0 >= L) return;
  const int b = bh >> 3, h = bh & 7;
  const int Lrem = L - q0;               // >= 1
  const int Nkb  = min(L, q0 + 64);      // keys needed by the whole block

  const int tid  = threadIdx.x;
  const int w    = tid >> 6;             // wave 0..3
  const int lane = tid & 63;
  const int Q = lane >> 4, c = lane & 15;

  __shared__ __align__(16) unsigned short Qs[64 * 72];  // 9216 B
  __shared__ __align__(16) unsigned short Ks[64 * 72];  // 9216 B
  __shared__ __align__(16) unsigned short Vt[64 * 72];  // 9216 B, [d][key]

  const size_t rowb = (size_t)b * T_ * QKVS + (size_t)h * HD_;

  // ---- stage Q stripe (64 rows x 64 halfs): 32 B per thread ----
  {
    const int u = tid >> 2, ch4 = (tid & 3) * 16;
    const int t = q0 + min(u, Lrem - 1);            // clamp (dup row, masked)
    const unsigned short* gq = qkv + rowb + (size_t)(r + t * p) * QKVS + ch4;
    int4 v0 = ((const int4*)gq)[0];
    int4 v1 = ((const int4*)gq)[1];
    *(int4*)&Qs[u * 72 + ch4 + 0] = v0;
    *(int4*)&Qs[u * 72 + ch4 + 8] = v1;
  }
  __syncthreads();
  bf16x8 qf[2];                          // B-frag: B[k=d=Q*8+j(+32)][n=q=c]
  qf[0] = *(const bf16x8*)&Qs[(w * 16 + c) * 72 + Q * 8];
  qf[1] = *(const bf16x8*)&Qs[(w * 16 + c) * 72 + Q * 8 + 32];

  const int qb      = w * 16;            // wave's query offset in stripe
  const int nqw     = min(16, Lrem - qb);// <=0 -> inactive wave (barriers only)
  const int qglob   = q0 + qb + c;       // this lane's query t-index
  const int mylastk = q0 + qb + 15;      // last key this wave can need

  float m_run = -3.0e38f, l_run = 0.f;
  f32x4 o[4] = {};
  const size_t kb = rowb + D_;
  const size_t vb = rowb + 2 * D_;

  // staging assignments (256 threads, 64-key tiles)
  const int krow = tid >> 2, koff = (tid & 3) * 16;     // K: 2x16B/thread
  const int vkey = tid & 63, vd0 = (tid >> 6) * 8;      // V: 2x16B/thread

  // ---- prefetch round 0 ----
  int4 kp0, kp1, vp0, vp1;
  {
    const int tk = min(krow, Nkb - 1);
    const int tv = min(vkey, Nkb - 1);
    const unsigned short* gk = qkv + kb + (size_t)(r + tk * p) * QKVS + koff;
    const unsigned short* gv = qkv + vb + (size_t)(r + tv * p) * QKVS;
    kp0 = ((const int4*)gk)[0];
    kp1 = ((const int4*)gk)[1];
    vp0 = *(const int4*)(gv + vd0);
    vp1 = *(const int4*)(gv + vd0 + 32);
  }

  for (int k0 = 0; k0 < Nkb; k0 += 64) {
    __syncthreads();                     // prev round's frag reads complete
    // ---- commit prefetched K (row-major) + V (transposed) ----
    {
      *(int4*)&Ks[krow * 72 + koff + 0] = kp0;
      *(int4*)&Ks[krow * 72 + koff + 8] = kp1;
      unsigned short vh0[8], vh1[8];
      *(int4*)vh0 = vp0;
      *(int4*)vh1 = vp1;
      #pragma unroll
      for (int j = 0; j < 8; ++j) {
        Vt[(vd0 + j) * 72 + vkey]      = vh0[j];
        Vt[(vd0 + 32 + j) * 72 + vkey] = vh1[j];
      }
    }
    __syncthreads();                     // LDS valid

    // ---- issue next round's global loads (hide behind compute) ----
    if (k0 + 64 < Nkb) {
      const int tk = min(k0 + 64 + krow, Nkb - 1);
      const int tv = min(k0 + 64 + vkey, Nkb - 1);
      const unsigned short* gk = qkv + kb + (size_t)(r + tk * p) * QKVS + koff;
      const unsigned short* gv = qkv + vb + (size_t)(r + tv * p) * QKVS;
      kp0 = ((const int4*)gk)[0];
      kp1 = ((const int4*)gk)[1];
      vp0 = *(const int4*)(gv + vd0);
      vp1 = *(const int4*)(gv + vd0 + 32);
    }

    if (nqw > 0 && k0 <= mylastk) {
      // ---- S^T tiles (4 x 16 keys), per-tile skip ----
      float pvv[16];
      float tmax = -3.0e38f;
      #pragma unroll
      for (int mt = 0; mt < 4; ++mt) {
        if (k0 + mt * 16 <= mylastk) {
          bf16x8 a0 = *(const bf16x8*)&Ks[(mt * 16 + c) * 72 + Q * 8];
          bf16x8 a1 = *(const bf16x8*)&Ks[(mt * 16 + c) * 72 + Q * 8 + 32];
          f32x4 s = {};
          s = __builtin_amdgcn_mfma_f32_16x16x32_bf16(a0, qf[0], s, 0, 0, 0);
          s = __builtin_amdgcn_mfma_f32_16x16x32_bf16(a1, qf[1], s, 0, 0, 0);
          #pragma unroll
          for (int rg = 0; rg < 4; ++rg) {
            const int kk = k0 + mt * 16 + Q * 4 + rg;   // key t-index
            float v = s[rg] * 0.125f;                   // 1/sqrt(HD)
            v = (kk <= qglob) ? v : -3.0e38f;
            pvv[mt * 4 + rg] = v;
            tmax = fmaxf(tmax, v);
          }
        } else {
          #pragma unroll
          for (int rg = 0; rg < 4; ++rg) pvv[mt * 4 + rg] = -3.0e38f;
        }
      }

      // ---- online softmax per column (q = c) ----
      tmax = fmaxf(tmax, __shfl_xor(tmax, 16));
      tmax = fmaxf(tmax, __shfl_xor(tmax, 32));
      const float m_new = fmaxf(m_run, tmax);
      const float alpha = __expf(m_run - m_new);
      float tsum = 0.f;
      #pragma unroll
      for (int i = 0; i < 16; ++i) {
        pvv[i] = __expf(pvv[i] - m_new);
        tsum += pvv[i];
      }
      tsum += __shfl_xor(tsum, 16);
      tsum += __shfl_xor(tsum, 32);
      l_run = l_run * alpha + tsum;
      m_run = m_new;

      // ---- P^T -> B-operand frags per 32-key chunk ----
      bf16x8 pb[2];
      const int sq2 = (Q & 1) << 1;
      #pragma unroll
      for (int kc = 0; kc < 2; ++kc) {
        unsigned int pk0[2], pk1[2];
        pk0[0] = pack2bf(pvv[kc * 8 + 0], pvv[kc * 8 + 1]);
        pk0[1] = pack2bf(pvv[kc * 8 + 2], pvv[kc * 8 + 3]);
        pk1[0] = pack2bf(pvv[kc * 8 + 4], pvv[kc * 8 + 5]);
        pk1[1] = pack2bf(pvv[kc * 8 + 6], pvv[kc * 8 + 7]);
        int dw[4];
        #pragma unroll
        for (int d = 0; d < 4; ++d) {
          const int src = ((sq2 + (d >> 1)) << 4) + c;
          const int v0 = __shfl((int)pk0[d & 1], src);
          const int v1 = __shfl((int)pk1[d & 1], src);
          dw[d] = (Q >= 2) ? v1 : v0;
        }
        int4 bi = make_int4(dw[0], dw[1], dw[2], dw[3]);
        pb[kc] = *(bf16x8*)&bi;
      }

      // ---- O^T += V^T . P^T  (2 key-chunks x 4 d-chunks) ----
      #pragma unroll
      for (int ch = 0; ch < 4; ++ch)
        #pragma unroll
        for (int t2 = 0; t2 < 4; ++t2) o[ch][t2] *= alpha;
      #pragma unroll
      for (int kc = 0; kc < 2; ++kc) {
        if (k0 + kc * 32 <= mylastk) {
          #pragma unroll
          for (int ch = 0; ch < 4; ++ch) {
            bf16x8 af =
                *(const bf16x8*)&Vt[(ch * 16 + c) * 72 + kc * 32 + Q * 8];
            o[ch] = __builtin_amdgcn_mfma_f32_16x16x32_bf16(af, pb[kc], o[ch],
                                                            0, 0, 0);
          }
        }
      }
    }
  }

  // ---- epilogue: O[q][d] = O^T[d][q] / l ----
  if (nqw > 0 && c < nqw) {
    const float invl = 1.f / l_run;
    const int tok = r + (q0 + qb + c) * p;
    unsigned int* dst =
        (unsigned int*)(ao + (size_t)(b * T_ + tok) * D_ + h * HD_);
    #pragma unroll
    for (int ch = 0; ch < 4; ++ch)
      #pragma unroll
      for (int rp = 0; rp < 2; ++rp) {
        const int dhalf = ch * 16 + Q * 4 + rp * 2;   // even
        dst[dhalf >> 1] =
            pack2bf(o[ch][rp * 2] * invl, o[ch][rp * 2 + 1] * invl);
      }
  }
}

// ---------------------------------------------------------------------------
extern "C" void kernel_launch(void* const* d_in, const int* in_sizes, int n_in,
                              void* d_out, int out_size, void* d_ws, size_t ws_size,
                              hipStream_t stream) {
  const float* x      = (const float*)d_in[0];   // (B,T,D)
  const int*   period = (const int*)  d_in[1];   // (B,H)
  const float* w_qkv  = (const float*)d_in[2];   // (3D, D)
  const float* b_qkv  = (const float*)d_in[3];   // (3D,)
  const float* w_out  = (const float*)d_in[4];   // (D, D)
  const float* b_out  = (const float*)d_in[5];   // (D,)
  float* out = (float*)d_out;                    // (B,T,D)

  const int M = B_ * T_;                         // 4096

  // ws layout (MB): xb[0,4) wqb[4,5.5) wob[5.5,6) qkvb[6,18)
  char* ws = (char*)d_ws;
  unsigned short* xb   = (unsigned short*)(ws);
  unsigned short* wqb  = (unsigned short*)(ws + (size_t)M * D_ * 2);
  unsigned short* wob  = (unsigned short*)(ws + (size_t)M * D_ * 2
                                              + (size_t)QKVS * D_ * 2);
  unsigned short* qkvb = (unsigned short*)(ws + (size_t)M * D_ * 2
                                              + (size_t)QKVS * D_ * 2
                                              + (size_t)D_ * D_ * 2);
  unsigned short* aob  = xb;   // alias: x_bf16 dead after GEMM1

  // fused input casts
  {
    const int n4 = (M * D_ + QKVS * D_ + D_ * D_) / 4;
    cast_all<<<dim3((n4 + 255) / 256), dim3(256), 0, stream>>>(
        x, w_qkv, w_out, xb, wqb, wob);
  }

  // 1) QKV projection -> bf16 token-major qkvb (128x64 tile, BK=128, grid 768)
  gemm_nt_bk128<1><<<dim3(QKVS / 64, M / 128), dim3(256), 0, stream>>>(
      xb, wqb, b_qkv, qkvb, M, QKVS, D_);

  // 2) residue-class flash attention (64-query stripes, 64-key rounds) -> aob
  attn_flash4<<<dim3(16, 63), dim3(256), 0, stream>>>(qkvb, period, aob);

  // 3) output projection -> fp32 out (128x64 tile, BK=128, grid 256)
  gemm_nt_bk128<0><<<dim3(D_ / 64, M / 128), dim3(256), 0, stream>>>(
      aob, wob, b_out, out, M, D_, D_);
}